// Round 8
// baseline (220.208 us; speedup 1.0000x reference)
//
#include <hip/hip_runtime.h>
#include <hip/hip_bf16.h>

constexpr int B = 8;
constexpr int C = 512;
constexpr int M = 64;
constexpr int N = 4096;
constexpr float EPS = 1e-6f;
constexpr int NTS = 16;   // n-split for s_kernel -> (8,16,8)=1024 blocks, 4 iters each
constexpr int LDP = 72;   // bf16 LDS row pitch (144B)
constexpr int LDPF = 68;  // f32 bounce row pitch

typedef __attribute__((ext_vector_type(8))) short short8v;
typedef __attribute__((ext_vector_type(4))) short short4v;
typedef __attribute__((ext_vector_type(4))) float f32x4;

__device__ __forceinline__ short f2b(float f) {
  union { __hip_bfloat16 h; short s; } u;
  u.h = __float2bfloat16(f);
  return u.s;
}
__device__ __forceinline__ float b2f(short s) {
  union { __hip_bfloat16 h; short s2; } u;
  u.s2 = s;
  return __bfloat162float(u.h);
}

// ---------------------------------------------------------------------------
// prep0: weights f32 -> bf16, zero Ksum & xsum accumulators.
// ---------------------------------------------------------------------------
__global__ __launch_bounds__(256) void prep_kernel(
    const float* __restrict__ Wq, const float* __restrict__ Wk,
    const float* __restrict__ Wv, short* __restrict__ Wq_bf,
    short* __restrict__ Wk_bf, short* __restrict__ Wv_bf,
    float* __restrict__ Ksum, float* __restrict__ xsum) {
  const int id = blockIdx.x * 256 + threadIdx.x;
  const int stride = gridDim.x * 256;
  for (int i = id; i < C * M / 4; i += stride) {
    const float4 a = reinterpret_cast<const float4*>(Wq)[i];
    const float4 b = reinterpret_cast<const float4*>(Wk)[i];
    short4v sa = {f2b(a.x), f2b(a.y), f2b(a.z), f2b(a.w)};
    short4v sb = {f2b(b.x), f2b(b.y), f2b(b.z), f2b(b.w)};
    reinterpret_cast<short4v*>(Wq_bf)[i] = sa;
    reinterpret_cast<short4v*>(Wk_bf)[i] = sb;
  }
  for (int i = id; i < C * C / 4; i += stride) {
    const float4 a = reinterpret_cast<const float4*>(Wv)[i];
    short4v sa = {f2b(a.x), f2b(a.y), f2b(a.z), f2b(a.w)};
    reinterpret_cast<short4v*>(Wv_bf)[i] = sa;
  }
  for (int i = id; i < B * M + B * C; i += stride) {
    if (i < B * M) Ksum[i] = 0.f;
    else xsum[i - B * M] = 0.f;
  }
}

// ---------------------------------------------------------------------------
// prepx: one streaming pass over x producing
//   x_bf [b][c][n]  (bf16, row-major copy)
//   xT_bf[b][n][c]  (bf16, transposed via LDS tile)
//   xsum [b][c]     (row sums, one atomicAdd per row per tile)
// Grid (N/64, C/64, B); 64x64 tile per block, coalesced on both sides.
// ---------------------------------------------------------------------------
__global__ __launch_bounds__(256) void prepx_kernel(
    const float* __restrict__ x, short* __restrict__ x_bf,
    short* __restrict__ xT_bf, float* __restrict__ xsum) {
  __shared__ short lt[64 * LDP];  // [n][c]
  __shared__ float red[256];
  const int t = threadIdx.x;
  const int nb = blockIdx.x * 64;
  const int cb = blockIdx.y * 64;
  const int b = blockIdx.z;
  const int r = t >> 2, q = t & 3;  // c-row, n-quarter
  const float* xp = x + ((size_t)b * C + cb + r) * N + nb + q * 16;
  float4 v[4];
#pragma unroll
  for (int i = 0; i < 4; ++i) v[i] = *reinterpret_cast<const float4*>(xp + 4 * i);
  short tmp[16];
  float s = 0.f;
#pragma unroll
  for (int i = 0; i < 4; ++i) {
    tmp[4 * i + 0] = f2b(v[i].x); tmp[4 * i + 1] = f2b(v[i].y);
    tmp[4 * i + 2] = f2b(v[i].z); tmp[4 * i + 3] = f2b(v[i].w);
    s += v[i].x + v[i].y + v[i].z + v[i].w;
  }
  {  // x_bf row-major write (coalesced)
    short* dst = x_bf + ((size_t)b * C + cb + r) * N + nb + q * 16;
    *reinterpret_cast<short8v*>(dst) = *reinterpret_cast<const short8v*>(&tmp[0]);
    *reinterpret_cast<short8v*>(dst + 8) = *reinterpret_cast<const short8v*>(&tmp[8]);
  }
#pragma unroll
  for (int i = 0; i < 16; ++i) lt[(q * 16 + i) * LDP + r] = tmp[i];  // transpose into LDS
  red[t] = s;
  __syncthreads();
  if (t < 64) {
    const float rs = red[4 * t] + red[4 * t + 1] + red[4 * t + 2] + red[4 * t + 3];
    atomicAdd(&xsum[b * C + cb + t], rs);
  }
  {  // xT_bf write (coalesced): row n = t>>2, cols cb + q*16..
    const int n = t >> 2;
    short* dst = xT_bf + ((size_t)b * N + nb + n) * C + cb + q * 16;
    *reinterpret_cast<short8v*>(dst) = *reinterpret_cast<const short8v*>(&lt[n * LDP + q * 16]);
    *reinterpret_cast<short8v*>(dst + 8) = *reinterpret_cast<const short8v*>(&lt[n * LDP + q * 16 + 8]);
  }
}

// ---------------------------------------------------------------------------
// qk: D[m][n] = Wq/Wk[m][cK] x xT[n][cK] via MFMA; L2-normalize per n;
// writes QnT_bf[b][n][m], Kn_bf[b][m][n]; Ksum via shfl+atomics.
// All staging is pure 16B LDS copies (xT_bf pre-transposed).
// ---------------------------------------------------------------------------
__global__ __launch_bounds__(256) void qk_kernel(
    const short* __restrict__ xT_bf, const short* __restrict__ Wq_bf,
    const float* __restrict__ bq, const short* __restrict__ Wk_bf,
    const float* __restrict__ bk, short* __restrict__ QnT,
    short* __restrict__ KnB, float* __restrict__ Ksum) {
  __shared__ short aq[64 * LDP];  // Wq tile [m][cK]
  __shared__ short ak[64 * LDP];  // Wk tile [m][cK]
  __shared__ short bx[64 * LDP];  // xT tile [n][cK]
  __shared__ float colred[2][4][64];
  __shared__ float rsq[2][64];
  const int t = threadIdx.x;
  const int n0 = blockIdx.x * 64;
  const int b = blockIdx.y;
  const int w = t >> 6, l = t & 63, l15 = l & 15, kg = l >> 4;
  const int sr = t >> 2, sko = (t & 3) * 16;
  f32x4 accQ[4], accK[4];
#pragma unroll
  for (int i = 0; i < 4; ++i) { accQ[i] = f32x4{0.f, 0.f, 0.f, 0.f}; accK[i] = f32x4{0.f, 0.f, 0.f, 0.f}; }

  for (int c0 = 0; c0 < C; c0 += 64) {
    __syncthreads();
    *reinterpret_cast<short8v*>(&aq[sr * LDP + sko]) =
        *reinterpret_cast<const short8v*>(&Wq_bf[sr * C + c0 + sko]);
    *reinterpret_cast<short8v*>(&aq[sr * LDP + sko + 8]) =
        *reinterpret_cast<const short8v*>(&Wq_bf[sr * C + c0 + sko + 8]);
    *reinterpret_cast<short8v*>(&ak[sr * LDP + sko]) =
        *reinterpret_cast<const short8v*>(&Wk_bf[sr * C + c0 + sko]);
    *reinterpret_cast<short8v*>(&ak[sr * LDP + sko + 8]) =
        *reinterpret_cast<const short8v*>(&Wk_bf[sr * C + c0 + sko + 8]);
    const short* xg = &xT_bf[((size_t)b * N + n0 + sr) * C + c0 + sko];
    *reinterpret_cast<short8v*>(&bx[sr * LDP + sko]) = *reinterpret_cast<const short8v*>(xg);
    *reinterpret_cast<short8v*>(&bx[sr * LDP + sko + 8]) = *reinterpret_cast<const short8v*>(xg + 8);
    __syncthreads();
#pragma unroll
    for (int ks = 0; ks < 2; ++ks) {
      const short8v afq = *reinterpret_cast<const short8v*>(&aq[(w * 16 + l15) * LDP + ks * 32 + kg * 8]);
      const short8v afk = *reinterpret_cast<const short8v*>(&ak[(w * 16 + l15) * LDP + ks * 32 + kg * 8]);
#pragma unroll
      for (int tc = 0; tc < 4; ++tc) {
        const short8v bf = *reinterpret_cast<const short8v*>(&bx[(tc * 16 + l15) * LDP + ks * 32 + kg * 8]);
        accQ[tc] = __builtin_amdgcn_mfma_f32_16x16x32_bf16(afq, bf, accQ[tc], 0, 0, 0);
        accK[tc] = __builtin_amdgcn_mfma_f32_16x16x32_bf16(afk, bf, accK[tc], 0, 0, 0);
      }
    }
  }
  // bias (row = w*16 + kg*4 + reg)
  {
    const float4 q4 = *reinterpret_cast<const float4*>(&bq[w * 16 + kg * 4]);
    const float4 k4 = *reinterpret_cast<const float4*>(&bk[w * 16 + kg * 4]);
    const float bqa[4] = {q4.x, q4.y, q4.z, q4.w};
    const float bka[4] = {k4.x, k4.y, k4.z, k4.w};
#pragma unroll
    for (int tc = 0; tc < 4; ++tc)
#pragma unroll
      for (int r = 0; r < 4; ++r) { accQ[tc][r] += bqa[r]; accK[tc][r] += bka[r]; }
  }
  // per-position (n) sum of squares over m
#pragma unroll
  for (int tc = 0; tc < 4; ++tc) {
    float vq = accQ[tc][0] * accQ[tc][0] + accQ[tc][1] * accQ[tc][1] +
               accQ[tc][2] * accQ[tc][2] + accQ[tc][3] * accQ[tc][3];
    float vk = accK[tc][0] * accK[tc][0] + accK[tc][1] * accK[tc][1] +
               accK[tc][2] * accK[tc][2] + accK[tc][3] * accK[tc][3];
    vq += __shfl_xor(vq, 16, 64); vq += __shfl_xor(vq, 32, 64);
    vk += __shfl_xor(vk, 16, 64); vk += __shfl_xor(vk, 32, 64);
    if (l < 16) { colred[0][w][tc * 16 + l] = vq; colred[1][w][tc * 16 + l] = vk; }
  }
  __syncthreads();
  if (t < 128) {
    const int which = t >> 6, n = t & 63;
    const float s = colred[which][0][n] + colred[which][1][n] +
                    colred[which][2][n] + colred[which][3][n];
    rsq[which][n] = 1.0f / sqrtf(s);
  }
  __syncthreads();
  // normalize + Ksum row partials
  float ksr[4] = {0.f, 0.f, 0.f, 0.f};
#pragma unroll
  for (int tc = 0; tc < 4; ++tc) {
    const float rq = rsq[0][tc * 16 + l15], rk = rsq[1][tc * 16 + l15];
#pragma unroll
    for (int r = 0; r < 4; ++r) { accQ[tc][r] *= rq; accK[tc][r] *= rk; ksr[r] += accK[tc][r]; }
  }
#pragma unroll
  for (int r = 0; r < 4; ++r) {
    float s = ksr[r];
    s += __shfl_xor(s, 1, 64); s += __shfl_xor(s, 2, 64);
    s += __shfl_xor(s, 4, 64); s += __shfl_xor(s, 8, 64);
    if (l15 == 0) atomicAdd(&Ksum[b * M + w * 16 + kg * 4 + r], s);
  }
  // bounce: QnT into aq [n][m], Kn into ak [m][n]
#pragma unroll
  for (int tc = 0; tc < 4; ++tc) {
    short4v q4 = {f2b(accQ[tc][0]), f2b(accQ[tc][1]), f2b(accQ[tc][2]), f2b(accQ[tc][3])};
    *reinterpret_cast<short4v*>(&aq[(tc * 16 + l15) * LDP + w * 16 + kg * 4]) = q4;
#pragma unroll
    for (int r = 0; r < 4; ++r)
      ak[(w * 16 + kg * 4 + r) * LDP + tc * 16 + l15] = f2b(accK[tc][r]);
  }
  __syncthreads();
  {
    short* qg = QnT + ((size_t)b * N + n0 + sr) * M + sko;
    *reinterpret_cast<short8v*>(qg) = *reinterpret_cast<const short8v*>(&aq[sr * LDP + sko]);
    *reinterpret_cast<short8v*>(qg + 8) = *reinterpret_cast<const short8v*>(&aq[sr * LDP + sko + 8]);
    short* kg2 = KnB + ((size_t)b * M + sr) * N + n0 + sko;
    *reinterpret_cast<short8v*>(kg2) = *reinterpret_cast<const short8v*>(&ak[sr * LDP + sko]);
    *reinterpret_cast<short8v*>(kg2 + 8) = *reinterpret_cast<const short8v*>(&ak[sr * LDP + sko + 8]);
  }
}

// ---------------------------------------------------------------------------
// s: S'[m][c'] = Kn[m][nK] x x[c'][nK] over this block's n-range; bf16
// partials (no atomics). Pure-copy staging from bf16 sources.
// ---------------------------------------------------------------------------
__global__ __launch_bounds__(256) void s_kernel(
    const short* __restrict__ x_bf, const short* __restrict__ KnB,
    short* __restrict__ Spart) {
  __shared__ short sm[2 * 64 * LDP];  // ka | xb ; reused as bf16 bounce
  short* ka = sm;
  short* xb = sm + 64 * LDP;
  const int t = threadIdx.x;
  const int c0 = blockIdx.x * 64;
  const int nt = blockIdx.y;
  const int b = blockIdx.z;
  const int w = t >> 6, l = t & 63, l15 = l & 15, kg = l >> 4;
  const int sr = t >> 2, sko = (t & 3) * 16;
  f32x4 acc[4];
#pragma unroll
  for (int i = 0; i < 4; ++i) acc[i] = f32x4{0.f, 0.f, 0.f, 0.f};
  constexpr int ITERS = N / NTS / 64;  // 4
  const int nbase = nt * (N / NTS);
  for (int it = 0; it < ITERS; ++it) {
    const int nk = nbase + it * 64;
    __syncthreads();
    {
      const short* kp = &KnB[((size_t)b * M + sr) * N + nk + sko];
      *reinterpret_cast<short8v*>(&ka[sr * LDP + sko]) = *reinterpret_cast<const short8v*>(kp);
      *reinterpret_cast<short8v*>(&ka[sr * LDP + sko + 8]) = *reinterpret_cast<const short8v*>(kp + 8);
      const short* xp = &x_bf[((size_t)b * C + c0 + sr) * N + nk + sko];
      *reinterpret_cast<short8v*>(&xb[sr * LDP + sko]) = *reinterpret_cast<const short8v*>(xp);
      *reinterpret_cast<short8v*>(&xb[sr * LDP + sko + 8]) = *reinterpret_cast<const short8v*>(xp + 8);
    }
    __syncthreads();
#pragma unroll
    for (int ks = 0; ks < 2; ++ks) {
      const short8v af = *reinterpret_cast<const short8v*>(&ka[(w * 16 + l15) * LDP + ks * 32 + kg * 8]);
#pragma unroll
      for (int tc = 0; tc < 4; ++tc) {
        const short8v bf = *reinterpret_cast<const short8v*>(&xb[(tc * 16 + l15) * LDP + ks * 32 + kg * 8]);
        acc[tc] = __builtin_amdgcn_mfma_f32_16x16x32_bf16(af, bf, acc[tc], 0, 0, 0);
      }
    }
  }
  __syncthreads();  // all MFMA LDS reads done before bounce overwrite
  // bounce S' bf16 [m][c'] into sm
#pragma unroll
  for (int tc = 0; tc < 4; ++tc)
#pragma unroll
    for (int r = 0; r < 4; ++r)
      sm[(w * 16 + kg * 4 + r) * LDP + tc * 16 + l15] = f2b(acc[tc][r]);
  __syncthreads();
  {
    short* gp = Spart + (((size_t)nt * B + b) * M + sr) * C + c0 + sko;
    *reinterpret_cast<short8v*>(gp) = *reinterpret_cast<const short8v*>(&sm[sr * LDP + sko]);
    *reinterpret_cast<short8v*>(gp + 8) = *reinterpret_cast<const short8v*>(&sm[sr * LDP + sko + 8]);
  }
}

// ---------------------------------------------------------------------------
// matm: matMT[c][m] = Wv[c][c'K] x S'[m][c'K] + bv[c]*Ksum[m]  (bf16 out)
// Staging folds the NTS bf16 partials of S'. Fused vsum GEMV.
// ---------------------------------------------------------------------------
__global__ __launch_bounds__(256) void matm_kernel(
    const short* __restrict__ Wv_bf, const float* __restrict__ bv,
    const short* __restrict__ Spart, const float* __restrict__ xsum,
    const float* __restrict__ Ksum, short* __restrict__ matMT,
    float* __restrict__ vsum) {
  __shared__ short wa[64 * LDP];
  __shared__ short sb[64 * LDP];
  __shared__ float xs[64];
  const int t = threadIdx.x;
  const int c0 = blockIdx.x * 64;
  const int b = blockIdx.y;
  const int w = t >> 6, l = t & 63, l15 = l & 15, kg = l >> 4;
  const int sr = t >> 2, sko = (t & 3) * 16;
  f32x4 acc[4];
#pragma unroll
  for (int i = 0; i < 4; ++i) acc[i] = f32x4{0.f, 0.f, 0.f, 0.f};
  float vacc = 0.f;
  for (int k0 = 0; k0 < C; k0 += 64) {
    __syncthreads();
    *reinterpret_cast<short8v*>(&wa[sr * LDP + sko]) =
        *reinterpret_cast<const short8v*>(&Wv_bf[(size_t)(c0 + sr) * C + k0 + sko]);
    *reinterpret_cast<short8v*>(&wa[sr * LDP + sko + 8]) =
        *reinterpret_cast<const short8v*>(&Wv_bf[(size_t)(c0 + sr) * C + k0 + sko + 8]);
    {  // fold NTS partials of S'[m=sr][k0+sko .. +15]
      float sacc[16];
#pragma unroll
      for (int j = 0; j < 16; ++j) sacc[j] = 0.f;
#pragma unroll 4
      for (int nt2 = 0; nt2 < NTS; ++nt2) {
        const short* sp = Spart + (((size_t)nt2 * B + b) * M + sr) * C + k0 + sko;
        const short8v p0 = *reinterpret_cast<const short8v*>(sp);
        const short8v p1 = *reinterpret_cast<const short8v*>(sp + 8);
#pragma unroll
        for (int j = 0; j < 8; ++j) { sacc[j] += b2f(p0[j]); sacc[8 + j] += b2f(p1[j]); }
      }
      short tmp[16];
#pragma unroll
      for (int j = 0; j < 16; ++j) tmp[j] = f2b(sacc[j]);
      *reinterpret_cast<short8v*>(&sb[sr * LDP + sko]) = *reinterpret_cast<const short8v*>(&tmp[0]);
      *reinterpret_cast<short8v*>(&sb[sr * LDP + sko + 8]) = *reinterpret_cast<const short8v*>(&tmp[8]);
    }
    if (t < 64) xs[t] = xsum[b * C + k0 + t];
    __syncthreads();
#pragma unroll
    for (int ks = 0; ks < 2; ++ks) {
      const short8v af = *reinterpret_cast<const short8v*>(&wa[(w * 16 + l15) * LDP + ks * 32 + kg * 8]);
#pragma unroll
      for (int tc = 0; tc < 4; ++tc) {
        const short8v bf = *reinterpret_cast<const short8v*>(&sb[(tc * 16 + l15) * LDP + ks * 32 + kg * 8]);
        acc[tc] = __builtin_amdgcn_mfma_f32_16x16x32_bf16(af, bf, acc[tc], 0, 0, 0);
      }
    }
    if (t < 64) {
      float v = 0.f;
#pragma unroll 8
      for (int kk = 0; kk < 64; ++kk) v = fmaf(b2f(wa[t * LDP + kk]), xs[kk], v);
      vacc += v;
    }
  }
  __syncthreads();
  {  // epilogue: + bv[c]*Ksum[m], bounce bf16 [c][m] into wa
    const float4 b4 = *reinterpret_cast<const float4*>(&bv[c0 + w * 16 + kg * 4]);
    const float bva[4] = {b4.x, b4.y, b4.z, b4.w};
#pragma unroll
    for (int tc = 0; tc < 4; ++tc) {
      const float ksm = Ksum[b * M + tc * 16 + l15];
#pragma unroll
      for (int r = 0; r < 4; ++r)
        wa[(w * 16 + kg * 4 + r) * LDP + tc * 16 + l15] = f2b(acc[tc][r] + bva[r] * ksm);
    }
  }
  __syncthreads();
  {
    short* gp = matMT + ((size_t)b * C + c0 + sr) * M + sko;
    *reinterpret_cast<short8v*>(gp) = *reinterpret_cast<const short8v*>(&wa[sr * LDP + sko]);
    *reinterpret_cast<short8v*>(gp + 8) = *reinterpret_cast<const short8v*>(&wa[sr * LDP + sko + 8]);
  }
  if (t < 64) vsum[b * C + c0 + t] = vacc + 4096.0f * bv[c0 + t];
}

// ---------------------------------------------------------------------------
// final: D[c][n] = matMT[c][mK] x QnT[n][mK]; out = x + g*tl[n]*(vsum[c]+D).
// cy-split x2 (1024 blocks). Residual x read as bf16 (half traffic).
// ---------------------------------------------------------------------------
__global__ __launch_bounds__(256) void final_kernel(
    const short* __restrict__ x_bf, const short* __restrict__ QnT,
    const float* __restrict__ Ksum, const short* __restrict__ matMT,
    const float* __restrict__ vsum, const float* __restrict__ gamma,
    float* __restrict__ out) {
  __shared__ short qb[64 * LDP];   // B = QnT [n][m]
  __shared__ short ab[64 * LDP];   // A = matMT [c][m]
  __shared__ float bo[64 * LDPF];  // f32 bounce [c][n]
  __shared__ float ke[64];
  __shared__ float tl[64];
  __shared__ float red2[256];
  const int t = threadIdx.x;
  const int n0 = blockIdx.x * 64;
  const int cy = blockIdx.y;
  const int b = blockIdx.z;
  const int w = t >> 6, l = t & 63, l15 = l & 15, kg = l >> 4;
  const int sr = t >> 2, sko = (t & 3) * 16;
  {
    const short* qg = &QnT[((size_t)b * N + n0 + sr) * M + sko];
    *reinterpret_cast<short8v*>(&qb[sr * LDP + sko]) = *reinterpret_cast<const short8v*>(qg);
    *reinterpret_cast<short8v*>(&qb[sr * LDP + sko + 8]) = *reinterpret_cast<const short8v*>(qg + 8);
  }
  if (t < 64) ke[t] = Ksum[b * M + t] + EPS;
  __syncthreads();
  {
    const int n = t & 63, mq = t >> 6;
    float d = 0.f;
#pragma unroll
    for (int j = 0; j < 16; ++j) d = fmaf(b2f(qb[n * LDP + mq * 16 + j]), ke[mq * 16 + j], d);
    red2[t] = d;
  }
  __syncthreads();
  if (t < 64)
    tl[t] = 1.0f / (4096.0f + red2[t] + red2[64 + t] + red2[128 + t] + red2[192 + t]);
  const float g = gamma[0];
  for (int cc = 0; cc < 4; ++cc) {
    const int c0 = cy * 256 + cc * 64;
    __syncthreads();  // prev epilogue bo reads + prev MFMA ab reads done
    {
      const short* mp = &matMT[((size_t)b * C + c0 + sr) * M + sko];
      *reinterpret_cast<short8v*>(&ab[sr * LDP + sko]) = *reinterpret_cast<const short8v*>(mp);
      *reinterpret_cast<short8v*>(&ab[sr * LDP + sko + 8]) = *reinterpret_cast<const short8v*>(mp + 8);
    }
    __syncthreads();
    short8v xr0, xr1;  // this tile's residual x (bf16), loads hide under MFMA
    {
      const short* xp = &x_bf[((size_t)b * C + c0 + sr) * N + n0 + sko];
      xr0 = *reinterpret_cast<const short8v*>(xp);
      xr1 = *reinterpret_cast<const short8v*>(xp + 8);
    }
    f32x4 acc[4];
#pragma unroll
    for (int i = 0; i < 4; ++i) acc[i] = f32x4{0.f, 0.f, 0.f, 0.f};
#pragma unroll
    for (int ks = 0; ks < 2; ++ks) {
      const short8v af = *reinterpret_cast<const short8v*>(&ab[(w * 16 + l15) * LDP + ks * 32 + kg * 8]);
#pragma unroll
      for (int tc = 0; tc < 4; ++tc) {
        const short8v bf = *reinterpret_cast<const short8v*>(&qb[(tc * 16 + l15) * LDP + ks * 32 + kg * 8]);
        acc[tc] = __builtin_amdgcn_mfma_f32_16x16x32_bf16(af, bf, acc[tc], 0, 0, 0);
      }
    }
#pragma unroll
    for (int tc = 0; tc < 4; ++tc)
#pragma unroll
      for (int r = 0; r < 4; ++r)
        bo[(w * 16 + kg * 4 + r) * LDPF + tc * 16 + l15] = acc[tc][r];
    __syncthreads();
    {
      const int c = c0 + sr;
      const float vs = vsum[b * C + c];
      const size_t off = ((size_t)b * C + c) * N + n0 + sko;
#pragma unroll
      for (int i = 0; i < 4; ++i) {
        const float4 dv = *reinterpret_cast<const float4*>(&bo[sr * LDPF + sko + 4 * i]);
        const float4 tv = *reinterpret_cast<const float4*>(&tl[sko + 4 * i]);
        float4 o;
        o.x = b2f(i * 4 + 0 < 8 ? xr0[i * 4 + 0] : xr1[i * 4 - 8]) + g * tv.x * (vs + dv.x);
        o.y = b2f(i * 4 + 1 < 8 ? xr0[(i * 4 + 1) & 7] : xr1[(i * 4 + 1) & 7]) + g * tv.y * (vs + dv.y);
        o.z = b2f(i * 4 + 2 < 8 ? xr0[(i * 4 + 2) & 7] : xr1[(i * 4 + 2) & 7]) + g * tv.z * (vs + dv.z);
        o.w = b2f(i * 4 + 3 < 8 ? xr0[(i * 4 + 3) & 7] : xr1[(i * 4 + 3) & 7]) + g * tv.w * (vs + dv.w);
        *reinterpret_cast<float4*>(&out[off + 4 * i]) = o;
      }
    }
  }
}

// ---------------------------------------------------------------------------
extern "C" void kernel_launch(void* const* d_in, const int* in_sizes, int n_in,
                              void* d_out, int out_size, void* d_ws, size_t ws_size,
                              hipStream_t stream) {
  (void)in_sizes; (void)n_in; (void)out_size; (void)ws_size;
  const float* x = (const float*)d_in[0];
  const float* Wq = (const float*)d_in[1];
  const float* bq = (const float*)d_in[2];
  const float* Wk = (const float*)d_in[3];
  const float* bk = (const float*)d_in[4];
  const float* Wv = (const float*)d_in[5];
  const float* bv = (const float*)d_in[6];
  const float* gamma = (const float*)d_in[7];
  float* out = (float*)d_out;

  // ws layout, ~85 MB total
  char* wp = (char*)d_ws;
  short* Wq_bf = (short*)wp;  wp += (size_t)C * M * 2;
  short* Wk_bf = (short*)wp;  wp += (size_t)C * M * 2;
  short* Wv_bf = (short*)wp;  wp += (size_t)C * C * 2;
  short* x_bf  = (short*)wp;  wp += (size_t)B * C * N * 2;
  short* xT_bf = (short*)wp;  wp += (size_t)B * N * C * 2;
  short* KnB   = (short*)wp;  wp += (size_t)B * M * N * 2;
  short* QnT   = (short*)wp;  wp += (size_t)B * N * M * 2;
  short* matMT = (short*)wp;  wp += (size_t)B * C * M * 2;
  short* Spart = (short*)wp;  wp += (size_t)NTS * B * M * C * 2;
  float* Ksum  = (float*)wp;  wp += (size_t)B * M * 4;
  float* xsum  = (float*)wp;  wp += (size_t)B * C * 4;
  float* vsum  = (float*)wp;  wp += (size_t)B * C * 4;

  prep_kernel<<<256, 256, 0, stream>>>(Wq, Wk, Wv, Wq_bf, Wk_bf, Wv_bf, Ksum, xsum);
  prepx_kernel<<<dim3(N / 64, C / 64, B), 256, 0, stream>>>(x, x_bf, xT_bf, xsum);
  qk_kernel<<<dim3(N / 64, B), 256, 0, stream>>>(xT_bf, Wq_bf, bq, Wk_bf, bk, QnT, KnB, Ksum);
  s_kernel<<<dim3(C / 64, NTS, B), 256, 0, stream>>>(x_bf, KnB, Spart);
  matm_kernel<<<dim3(C / 64, B), 256, 0, stream>>>(Wv_bf, bv, Spart, xsum, Ksum, matMT, vsum);
  final_kernel<<<dim3(N / 64, 2, B), 256, 0, stream>>>(x_bf, QnT, Ksum, matMT, vsum, gamma, out);
}

// Round 10
// 185.752 us; speedup vs baseline: 1.1855x; 1.1855x over previous
//
#include <hip/hip_runtime.h>
#include <hip/hip_bf16.h>

constexpr int B = 8;
constexpr int C = 512;
constexpr int M = 64;
constexpr int N = 4096;
constexpr float EPS = 1e-6f;
constexpr int NPART = N / 64;  // 64 S'-partials (one per n-tile block)
constexpr int LDP = 72;        // bf16 LDS row pitch (144B)
constexpr int LDPF = 68;       // f32 bounce row pitch

typedef __attribute__((ext_vector_type(8))) short short8v;
typedef __attribute__((ext_vector_type(4))) short short4v;
typedef __attribute__((ext_vector_type(4))) float f32x4;

__device__ __forceinline__ short f2b(float f) {
  union { __hip_bfloat16 h; short s; } u;
  u.h = __float2bfloat16(f);
  return u.s;
}
__device__ __forceinline__ float b2f(short s) {
  union { __hip_bfloat16 h; short s2; } u;
  u.s2 = s;
  return __bfloat162float(u.h);
}

// ---------------------------------------------------------------------------
// prep: weights f32 -> bf16, zero Ksum & xsum accumulators.
// ---------------------------------------------------------------------------
__global__ __launch_bounds__(256) void prep_kernel(
    const float* __restrict__ Wq, const float* __restrict__ Wk,
    const float* __restrict__ Wv, short* __restrict__ Wq_bf,
    short* __restrict__ Wk_bf, short* __restrict__ Wv_bf,
    float* __restrict__ Ksum, float* __restrict__ xsum) {
  const int id = blockIdx.x * 256 + threadIdx.x;
  const int stride = gridDim.x * 256;
  for (int i = id; i < C * M / 4; i += stride) {
    const float4 a = reinterpret_cast<const float4*>(Wq)[i];
    const float4 b = reinterpret_cast<const float4*>(Wk)[i];
    short4v sa = {f2b(a.x), f2b(a.y), f2b(a.z), f2b(a.w)};
    short4v sb = {f2b(b.x), f2b(b.y), f2b(b.z), f2b(b.w)};
    reinterpret_cast<short4v*>(Wq_bf)[i] = sa;
    reinterpret_cast<short4v*>(Wk_bf)[i] = sb;
  }
  for (int i = id; i < C * C / 4; i += stride) {
    const float4 a = reinterpret_cast<const float4*>(Wv)[i];
    short4v sa = {f2b(a.x), f2b(a.y), f2b(a.z), f2b(a.w)};
    reinterpret_cast<short4v*>(Wv_bf)[i] = sa;
  }
  for (int i = id; i < B * M + B * C; i += stride) {
    if (i < B * M) Ksum[i] = 0.f;
    else xsum[i - B * M] = 0.f;
  }
}

// ---------------------------------------------------------------------------
// qks: fused qk + s. Phase 1 = Q/K GEMM over the block's 64-n window with
// x kept in registers (bf16) after conversion; L2-normalize; Ksum; write QnT.
// Kn stays in LDS. Phase 2 = S'[m][c'] = Kn[m][nK] x x[c'][nK] from regs,
// one 64-col chunk at a time; fuses xsum. Spart has NPART=64 partials.
// ---------------------------------------------------------------------------
__global__ __launch_bounds__(256, 2) void qks_kernel(
    const float* __restrict__ x, const short* __restrict__ Wq_bf,
    const float* __restrict__ bq, const short* __restrict__ Wk_bf,
    const float* __restrict__ bk, short* __restrict__ QnT,
    float* __restrict__ Ksum, short* __restrict__ Spart,
    float* __restrict__ xsum) {
  __shared__ short aq[64 * LDP];  // Wq tile [m][cK]; later Q bounce; later S' bounce
  __shared__ short ak[64 * LDP];  // Wk tile [m][cK]; later Kn [m][n]
  __shared__ short bx[64 * LDP];  // xT tile [n][cK]; later x chunk [c'][n]
  __shared__ float colred[2][4][64];
  __shared__ float rsq[2][64];
  __shared__ float red[256];
  const int t = threadIdx.x;
  const int nt = blockIdx.x;
  const int n0 = nt * 64;
  const int b = blockIdx.y;
  const int w = t >> 6, l = t & 63, l15 = l & 15, kg = l >> 4;
  const int sr = t >> 2, sko = (t & 3) * 16;
  const int cr = t & 63, ng = t >> 6;
  f32x4 accQ[4], accK[4];
#pragma unroll
  for (int i = 0; i < 4; ++i) { accQ[i] = f32x4{0.f, 0.f, 0.f, 0.f}; accK[i] = f32x4{0.f, 0.f, 0.f, 0.f}; }
  short8v xkeep[8][2];  // this thread's x row (c = p*64+cr), 16 n's, per chunk p

  // ---- phase 1: Q/K GEMM ----
#pragma unroll
  for (int p = 0; p < 8; ++p) {
    const int c0 = p * 64;
    __syncthreads();
    *reinterpret_cast<short8v*>(&aq[sr * LDP + sko]) =
        *reinterpret_cast<const short8v*>(&Wq_bf[sr * C + c0 + sko]);
    *reinterpret_cast<short8v*>(&aq[sr * LDP + sko + 8]) =
        *reinterpret_cast<const short8v*>(&Wq_bf[sr * C + c0 + sko + 8]);
    *reinterpret_cast<short8v*>(&ak[sr * LDP + sko]) =
        *reinterpret_cast<const short8v*>(&Wk_bf[sr * C + c0 + sko]);
    *reinterpret_cast<short8v*>(&ak[sr * LDP + sko + 8]) =
        *reinterpret_cast<const short8v*>(&Wk_bf[sr * C + c0 + sko + 8]);
    {  // load x row, convert, keep in regs + transposed LDS write
      const float* xg = x + ((size_t)b * C + c0 + cr) * N + n0 + ng * 16;
      float4 v[4];
#pragma unroll
      for (int i = 0; i < 4; ++i) v[i] = *reinterpret_cast<const float4*>(xg + 4 * i);
      short tmp[16];
#pragma unroll
      for (int i = 0; i < 4; ++i) {
        tmp[4 * i + 0] = f2b(v[i].x); tmp[4 * i + 1] = f2b(v[i].y);
        tmp[4 * i + 2] = f2b(v[i].z); tmp[4 * i + 3] = f2b(v[i].w);
      }
      xkeep[p][0] = *reinterpret_cast<const short8v*>(&tmp[0]);
      xkeep[p][1] = *reinterpret_cast<const short8v*>(&tmp[8]);
#pragma unroll
      for (int i = 0; i < 16; ++i) bx[(ng * 16 + i) * LDP + cr] = tmp[i];
    }
    __syncthreads();
#pragma unroll
    for (int ks = 0; ks < 2; ++ks) {
      const short8v afq = *reinterpret_cast<const short8v*>(&aq[(w * 16 + l15) * LDP + ks * 32 + kg * 8]);
      const short8v afk = *reinterpret_cast<const short8v*>(&ak[(w * 16 + l15) * LDP + ks * 32 + kg * 8]);
#pragma unroll
      for (int tc = 0; tc < 4; ++tc) {
        const short8v bf = *reinterpret_cast<const short8v*>(&bx[(tc * 16 + l15) * LDP + ks * 32 + kg * 8]);
        accQ[tc] = __builtin_amdgcn_mfma_f32_16x16x32_bf16(afq, bf, accQ[tc], 0, 0, 0);
        accK[tc] = __builtin_amdgcn_mfma_f32_16x16x32_bf16(afk, bf, accK[tc], 0, 0, 0);
      }
    }
  }
  // bias (row m = w*16 + kg*4 + r, col n = tc*16 + l15)
  {
    const float4 q4 = *reinterpret_cast<const float4*>(&bq[w * 16 + kg * 4]);
    const float4 k4 = *reinterpret_cast<const float4*>(&bk[w * 16 + kg * 4]);
    const float bqa[4] = {q4.x, q4.y, q4.z, q4.w};
    const float bka[4] = {k4.x, k4.y, k4.z, k4.w};
#pragma unroll
    for (int tc = 0; tc < 4; ++tc)
#pragma unroll
      for (int r = 0; r < 4; ++r) { accQ[tc][r] += bqa[r]; accK[tc][r] += bka[r]; }
  }
  // per-position (n) sum of squares over m
#pragma unroll
  for (int tc = 0; tc < 4; ++tc) {
    float vq = accQ[tc][0] * accQ[tc][0] + accQ[tc][1] * accQ[tc][1] +
               accQ[tc][2] * accQ[tc][2] + accQ[tc][3] * accQ[tc][3];
    float vk = accK[tc][0] * accK[tc][0] + accK[tc][1] * accK[tc][1] +
               accK[tc][2] * accK[tc][2] + accK[tc][3] * accK[tc][3];
    vq += __shfl_xor(vq, 16, 64); vq += __shfl_xor(vq, 32, 64);
    vk += __shfl_xor(vk, 16, 64); vk += __shfl_xor(vk, 32, 64);
    if (l < 16) { colred[0][w][tc * 16 + l] = vq; colred[1][w][tc * 16 + l] = vk; }
  }
  __syncthreads();
  if (t < 128) {
    const int which = t >> 6, n = t & 63;
    const float s = colred[which][0][n] + colred[which][1][n] +
                    colred[which][2][n] + colred[which][3][n];
    rsq[which][n] = 1.0f / sqrtf(s);
  }
  __syncthreads();
  // normalize + Ksum row partials
  float ksr[4] = {0.f, 0.f, 0.f, 0.f};
#pragma unroll
  for (int tc = 0; tc < 4; ++tc) {
    const float rq = rsq[0][tc * 16 + l15], rk = rsq[1][tc * 16 + l15];
#pragma unroll
    for (int r = 0; r < 4; ++r) { accQ[tc][r] *= rq; accK[tc][r] *= rk; ksr[r] += accK[tc][r]; }
  }
#pragma unroll
  for (int r = 0; r < 4; ++r) {
    float s = ksr[r];
    s += __shfl_xor(s, 1, 64); s += __shfl_xor(s, 2, 64);
    s += __shfl_xor(s, 4, 64); s += __shfl_xor(s, 8, 64);
    if (l15 == 0) atomicAdd(&Ksum[b * M + w * 16 + kg * 4 + r], s);
  }
  // bounce: Q into aq [n][m]; Kn into ak [m][n] (stays resident for phase 2)
#pragma unroll
  for (int tc = 0; tc < 4; ++tc) {
    short4v q4 = {f2b(accQ[tc][0]), f2b(accQ[tc][1]), f2b(accQ[tc][2]), f2b(accQ[tc][3])};
    *reinterpret_cast<short4v*>(&aq[(tc * 16 + l15) * LDP + w * 16 + kg * 4]) = q4;
#pragma unroll
    for (int r = 0; r < 4; ++r)
      ak[(w * 16 + kg * 4 + r) * LDP + tc * 16 + l15] = f2b(accK[tc][r]);
  }
  __syncthreads();
  {  // QnT global write
    short* qg = QnT + ((size_t)b * N + n0 + sr) * M + sko;
    *reinterpret_cast<short8v*>(qg) = *reinterpret_cast<const short8v*>(&aq[sr * LDP + sko]);
    *reinterpret_cast<short8v*>(qg + 8) = *reinterpret_cast<const short8v*>(&aq[sr * LDP + sko + 8]);
  }

  // ---- phase 2: S' = Kn x X over this n-window, 64-c' chunks from regs ----
#pragma unroll
  for (int p = 0; p < 8; ++p) {
    const int c0 = p * 64;
    __syncthreads();  // prior aq readers (QnT write / Spart write) done
    // x chunk [c'][n] from regs: row c' = cr, cols ng*16..
    *reinterpret_cast<short8v*>(&bx[cr * LDP + ng * 16]) = xkeep[p][0];
    *reinterpret_cast<short8v*>(&bx[cr * LDP + ng * 16 + 8]) = xkeep[p][1];
    __syncthreads();
    f32x4 sacc[4];
#pragma unroll
    for (int i = 0; i < 4; ++i) sacc[i] = f32x4{0.f, 0.f, 0.f, 0.f};
#pragma unroll
    for (int ks = 0; ks < 2; ++ks) {
      const short8v af = *reinterpret_cast<const short8v*>(&ak[(w * 16 + l15) * LDP + ks * 32 + kg * 8]);
#pragma unroll
      for (int tc = 0; tc < 4; ++tc) {
        const short8v bf = *reinterpret_cast<const short8v*>(&bx[(tc * 16 + l15) * LDP + ks * 32 + kg * 8]);
        sacc[tc] = __builtin_amdgcn_mfma_f32_16x16x32_bf16(af, bf, sacc[tc], 0, 0, 0);
      }
    }
    {  // xsum partial for row c = c0 + cr (from bf16 regs; post-tailor error negligible)
      float s = 0.f;
#pragma unroll
      for (int j = 0; j < 8; ++j) s += b2f(xkeep[p][0][j]) + b2f(xkeep[p][1][j]);
      red[t] = s;
    }
    __syncthreads();
    if (t < 64)
      atomicAdd(&xsum[b * C + c0 + t], red[t] + red[64 + t] + red[128 + t] + red[192 + t]);
    // bounce S' [m][c'chunk] into aq
#pragma unroll
    for (int tc = 0; tc < 4; ++tc)
#pragma unroll
      for (int r = 0; r < 4; ++r)
        aq[(w * 16 + kg * 4 + r) * LDP + tc * 16 + l15] = f2b(sacc[tc][r]);
    __syncthreads();
    {  // Spart[(nt*B+b)][m][c0+..] global write, rows m = sr
      short* gp = Spart + (((size_t)nt * B + b) * M + sr) * C + c0 + sko;
      *reinterpret_cast<short8v*>(gp) = *reinterpret_cast<const short8v*>(&aq[sr * LDP + sko]);
      *reinterpret_cast<short8v*>(gp + 8) = *reinterpret_cast<const short8v*>(&aq[sr * LDP + sko + 8]);
    }
  }
}

// ---------------------------------------------------------------------------
// sreduce: S_bf[b][m][c'] = bf16( sum over NPART bf16 partials )
// ---------------------------------------------------------------------------
__global__ __launch_bounds__(256) void sreduce_kernel(const short* __restrict__ Spart,
                                                      short* __restrict__ S_bf) {
  const int i2 = blockIdx.x * 256 + threadIdx.x;  // over B*M*C/2 = 131072
  const size_t stride = (size_t)B * M * C;
  const short* p = Spart + (size_t)i2 * 2;
  float s0 = 0.f, s1 = 0.f;
#pragma unroll 8
  for (int nt = 0; nt < NPART; ++nt) {
    const short* q = p + nt * stride;
    s0 += b2f(q[0]);
    s1 += b2f(q[1]);
  }
  short* o = S_bf + (size_t)i2 * 2;
  o[0] = f2b(s0);
  o[1] = f2b(s1);
}

// ---------------------------------------------------------------------------
// matm: matMT[c][m] = Wv[c][c'K] x S'[m][c'K] + bv[c]*Ksum[m]  (bf16 out)
// fused vsum[b][c] = Wv[c][:]·xsum[b][:] + N*bv[c]
// ---------------------------------------------------------------------------
__global__ __launch_bounds__(256) void matm_kernel(
    const short* __restrict__ Wv_bf, const float* __restrict__ bv,
    const short* __restrict__ S_bf, const float* __restrict__ xsum,
    const float* __restrict__ Ksum, short* __restrict__ matMT,
    float* __restrict__ vsum) {
  __shared__ short wa[64 * LDP];
  __shared__ short sb[64 * LDP];
  __shared__ float xs[64];
  const int t = threadIdx.x;
  const int c0 = blockIdx.x * 64;
  const int b = blockIdx.y;
  const int w = t >> 6, l = t & 63, l15 = l & 15, kg = l >> 4;
  const int sr = t >> 2, sko = (t & 3) * 16;
  f32x4 acc[4];
#pragma unroll
  for (int i = 0; i < 4; ++i) acc[i] = f32x4{0.f, 0.f, 0.f, 0.f};
  float vacc = 0.f;
  for (int k0 = 0; k0 < C; k0 += 64) {
    __syncthreads();
    *reinterpret_cast<short8v*>(&wa[sr * LDP + sko]) =
        *reinterpret_cast<const short8v*>(&Wv_bf[(size_t)(c0 + sr) * C + k0 + sko]);
    *reinterpret_cast<short8v*>(&wa[sr * LDP + sko + 8]) =
        *reinterpret_cast<const short8v*>(&Wv_bf[(size_t)(c0 + sr) * C + k0 + sko + 8]);
    *reinterpret_cast<short8v*>(&sb[sr * LDP + sko]) =
        *reinterpret_cast<const short8v*>(&S_bf[((size_t)b * M + sr) * C + k0 + sko]);
    *reinterpret_cast<short8v*>(&sb[sr * LDP + sko + 8]) =
        *reinterpret_cast<const short8v*>(&S_bf[((size_t)b * M + sr) * C + k0 + sko + 8]);
    if (t < 64) xs[t] = xsum[b * C + k0 + t];
    __syncthreads();
#pragma unroll
    for (int ks = 0; ks < 2; ++ks) {
      const short8v af = *reinterpret_cast<const short8v*>(&wa[(w * 16 + l15) * LDP + ks * 32 + kg * 8]);
#pragma unroll
      for (int tc = 0; tc < 4; ++tc) {
        const short8v bf = *reinterpret_cast<const short8v*>(&sb[(tc * 16 + l15) * LDP + ks * 32 + kg * 8]);
        acc[tc] = __builtin_amdgcn_mfma_f32_16x16x32_bf16(af, bf, acc[tc], 0, 0, 0);
      }
    }
    if (t < 64) {
      float v = 0.f;
#pragma unroll 8
      for (int kk = 0; kk < 64; ++kk) v = fmaf(b2f(wa[t * LDP + kk]), xs[kk], v);
      vacc += v;
    }
  }
  __syncthreads();
  {  // epilogue: + bv[c]*Ksum[m], bounce bf16 [c][m] into wa
    const float4 b4 = *reinterpret_cast<const float4*>(&bv[c0 + w * 16 + kg * 4]);
    const float bva[4] = {b4.x, b4.y, b4.z, b4.w};
#pragma unroll
    for (int tc = 0; tc < 4; ++tc) {
      const float ksm = Ksum[b * M + tc * 16 + l15];
#pragma unroll
      for (int r = 0; r < 4; ++r)
        wa[(w * 16 + kg * 4 + r) * LDP + tc * 16 + l15] = f2b(acc[tc][r] + bva[r] * ksm);
    }
  }
  __syncthreads();
  {
    short* gp = matMT + ((size_t)b * C + c0 + sr) * M + sko;
    *reinterpret_cast<short8v*>(gp) = *reinterpret_cast<const short8v*>(&wa[sr * LDP + sko]);
    *reinterpret_cast<short8v*>(gp + 8) = *reinterpret_cast<const short8v*>(&wa[sr * LDP + sko + 8]);
  }
  if (t < 64) vsum[b * C + c0 + t] = vacc + 4096.0f * bv[c0 + t];
}

// ---------------------------------------------------------------------------
// final: D[c][n] = matMT[c][mK] x QnT[n][mK]; out = x + g*tl[n]*(vsum[c]+D)
// tl[n] = 1/(N + sum_m QnT[n][m]*(Ksum[m]+EPS))
// ---------------------------------------------------------------------------
__global__ __launch_bounds__(256) void final_kernel(
    const float* __restrict__ x, const short* __restrict__ QnT,
    const float* __restrict__ Ksum, const short* __restrict__ matMT,
    const float* __restrict__ vsum, const float* __restrict__ gamma,
    float* __restrict__ out) {
  __shared__ short qb[64 * LDP];   // B = QnT [n][m]
  __shared__ short ab[64 * LDP];   // A = matMT [c][m]
  __shared__ float bo[64 * LDPF];  // f32 bounce [c][n]
  __shared__ float ke[64];
  __shared__ float tl[64];
  __shared__ float red2[256];
  const int t = threadIdx.x;
  const int n0 = blockIdx.x * 64;
  const int b = blockIdx.y;
  const int w = t >> 6, l = t & 63, l15 = l & 15, kg = l >> 4;
  const int sr = t >> 2, sko = (t & 3) * 16;
  {
    const short* qg = &QnT[((size_t)b * N + n0 + sr) * M + sko];
    *reinterpret_cast<short8v*>(&qb[sr * LDP + sko]) = *reinterpret_cast<const short8v*>(qg);
    *reinterpret_cast<short8v*>(&qb[sr * LDP + sko + 8]) = *reinterpret_cast<const short8v*>(qg + 8);
  }
  if (t < 64) ke[t] = Ksum[b * M + t] + EPS;
  __syncthreads();
  {
    const int n = t & 63, mq = t >> 6;
    float d = 0.f;
#pragma unroll
    for (int j = 0; j < 16; ++j) d = fmaf(b2f(qb[n * LDP + mq * 16 + j]), ke[mq * 16 + j], d);
    red2[t] = d;
  }
  __syncthreads();
  if (t < 64)
    tl[t] = 1.0f / (4096.0f + red2[t] + red2[64 + t] + red2[128 + t] + red2[192 + t]);
  const float g = gamma[0];
  for (int c0 = 0; c0 < C; c0 += 64) {
    __syncthreads();  // prior frag reads of ab + prior store reads of bo done
    {
      const short* mp = &matMT[((size_t)b * C + c0 + sr) * M + sko];
      *reinterpret_cast<short8v*>(&ab[sr * LDP + sko]) = *reinterpret_cast<const short8v*>(mp);
      *reinterpret_cast<short8v*>(&ab[sr * LDP + sko + 8]) = *reinterpret_cast<const short8v*>(mp + 8);
    }
    __syncthreads();
    f32x4 acc[4];
#pragma unroll
    for (int i = 0; i < 4; ++i) acc[i] = f32x4{0.f, 0.f, 0.f, 0.f};
#pragma unroll
    for (int ks = 0; ks < 2; ++ks) {
      const short8v af = *reinterpret_cast<const short8v*>(&ab[(w * 16 + l15) * LDP + ks * 32 + kg * 8]);
#pragma unroll
      for (int tc = 0; tc < 4; ++tc) {
        const short8v bf = *reinterpret_cast<const short8v*>(&qb[(tc * 16 + l15) * LDP + ks * 32 + kg * 8]);
        acc[tc] = __builtin_amdgcn_mfma_f32_16x16x32_bf16(af, bf, acc[tc], 0, 0, 0);
      }
    }
#pragma unroll
    for (int tc = 0; tc < 4; ++tc)
#pragma unroll
      for (int r = 0; r < 4; ++r)
        bo[(w * 16 + kg * 4 + r) * LDPF + tc * 16 + l15] = acc[tc][r];
    __syncthreads();
    {
      const int c = c0 + sr;
      const float vs = vsum[b * C + c];
      const size_t off = ((size_t)b * C + c) * N + n0 + sko;
#pragma unroll
      for (int i = 0; i < 4; ++i) {
        const float4 xv = *reinterpret_cast<const float4*>(&x[off + 4 * i]);
        const float4 dv = *reinterpret_cast<const float4*>(&bo[sr * LDPF + sko + 4 * i]);
        const float4 tv = *reinterpret_cast<const float4*>(&tl[sko + 4 * i]);
        float4 o;
        o.x = xv.x + g * tv.x * (vs + dv.x);
        o.y = xv.y + g * tv.y * (vs + dv.y);
        o.z = xv.z + g * tv.z * (vs + dv.z);
        o.w = xv.w + g * tv.w * (vs + dv.w);
        *reinterpret_cast<float4*>(&out[off + 4 * i]) = o;
      }
    }
  }
}

// ---------------------------------------------------------------------------
extern "C" void kernel_launch(void* const* d_in, const int* in_sizes, int n_in,
                              void* d_out, int out_size, void* d_ws, size_t ws_size,
                              hipStream_t stream) {
  (void)in_sizes; (void)n_in; (void)out_size; (void)ws_size;
  const float* x = (const float*)d_in[0];
  const float* Wq = (const float*)d_in[1];
  const float* bq = (const float*)d_in[2];
  const float* Wk = (const float*)d_in[3];
  const float* bk = (const float*)d_in[4];
  const float* Wv = (const float*)d_in[5];
  const float* bv = (const float*)d_in[6];
  const float* gamma = (const float*)d_in[7];
  float* out = (float*)d_out;

  // ws layout, ~43 MB total
  char* wp = (char*)d_ws;
  short* Wq_bf = (short*)wp;  wp += (size_t)C * M * 2;
  short* Wk_bf = (short*)wp;  wp += (size_t)C * M * 2;
  short* Wv_bf = (short*)wp;  wp += (size_t)C * C * 2;
  short* QnT   = (short*)wp;  wp += (size_t)B * N * M * 2;
  short* matMT = (short*)wp;  wp += (size_t)B * C * M * 2;
  short* S_bf  = (short*)wp;  wp += (size_t)B * M * C * 2;
  short* Spart = (short*)wp;  wp += (size_t)NPART * B * M * C * 2;
  float* Ksum  = (float*)wp;  wp += (size_t)B * M * 4;
  float* xsum  = (float*)wp;  wp += (size_t)B * C * 4;
  float* vsum  = (float*)wp;  wp += (size_t)B * C * 4;

  prep_kernel<<<256, 256, 0, stream>>>(Wq, Wk, Wv, Wq_bf, Wk_bf, Wv_bf, Ksum, xsum);
  qks_kernel<<<dim3(N / 64, B), 256, 0, stream>>>(x, Wq_bf, bq, Wk_bf, bk, QnT, Ksum, Spart, xsum);
  sreduce_kernel<<<B * M * C / 2 / 256, 256, 0, stream>>>(Spart, S_bf);
  matm_kernel<<<dim3(C / 64, B), 256, 0, stream>>>(Wv_bf, bv, S_bf, xsum, Ksum, matMT, vsum);
  final_kernel<<<dim3(N / 64, B), 256, 0, stream>>>(x, QnT, Ksum, matMT, vsum, gamma, out);
}